// Round 4
// baseline (88171.423 us; speedup 1.0000x reference)
//
#include <hip/hip_runtime.h>
#include <hip/hip_bf16.h>

#define TT 2048
#define BB 256
#define HH 128
#define UDIM 16
#define YDIM 16
#define ZDIM 32
#define H3 384

typedef __hip_bfloat16 bf16;

constexpr int clog2(int x) { return x <= 1 ? 0 : 1 + clog2(x >> 1); }

// ---------------------------------------------------------------------------
// Generic staged linear. THREADS threads, rg=tid/32 row-groups, jg=tid%32.
// Rows R=(THREADS/32)*RPT, cols j = jg+32*jj (jj<JJ). Input K = K1 (+K2 from
// a second LDS buffer, for concat inputs). Weights staged in KC-col chunks in
// LDS, stride KC+1 (odd -> scalar reads conflict-free). Data-buffer reads are
// 32-lane-uniform broadcasts (free), so data strides need only 16B alignment.
// OB16: write bf16 to global, else fp32.
// ---------------------------------------------------------------------------
template <int THREADS, int RPT, int JJ, int M, int K1, int K2, int KC, bool RELU, bool OB16>
__device__ void lin_stage(const float* __restrict__ inA, int sA,
                          const float* __restrict__ inB, int sB,
                          const float* __restrict__ Wg, const float* __restrict__ bg,
                          void* __restrict__ outp, int sO,
                          float* __restrict__ wlds)
{
    const int tid = threadIdx.x;
    const int rg = tid >> 5, jg = tid & 31;
    constexpr int K = K1 + K2;
    constexpr int LKC = clog2(KC);
    constexpr int WS = KC + 1;
    float acc[RPT][JJ];
#pragma unroll
    for (int jj = 0; jj < JJ; ++jj) {
        const int j = jg + 32 * jj;
        const float bv = (j < M) ? bg[j] : 0.f;
#pragma unroll
        for (int rr = 0; rr < RPT; ++rr) acc[rr][jj] = bv;
    }
#pragma unroll
    for (int k0 = 0; k0 < K; k0 += KC) {
        __syncthreads();  // prior wlds readers / prior-stage buffer writers done
        for (int idx = tid; idx < M * KC; idx += THREADS) {
            const int j = idx >> LKC, k = idx & (KC - 1);
            wlds[j * WS + k] = Wg[j * K + k0 + k];
        }
        __syncthreads();
        const float* src = (k0 < K1) ? (inA + k0) : (inB + (k0 - K1));
        const int ss = (k0 < K1) ? sA : sB;
#pragma unroll
        for (int k = 0; k < KC; k += 4) {
            float4 xin[RPT];
#pragma unroll
            for (int rr = 0; rr < RPT; ++rr) {
                const int r = rg * RPT + rr;
                xin[rr] = *reinterpret_cast<const float4*>(&src[r * ss + k]);
            }
#pragma unroll
            for (int jj = 0; jj < JJ; ++jj) {
                const int j = jg + 32 * jj;
                const float* wr = &wlds[j * WS + k];
                const float w0 = wr[0], w1 = wr[1], w2 = wr[2], w3 = wr[3];
#pragma unroll
                for (int rr = 0; rr < RPT; ++rr)
                    acc[rr][jj] += xin[rr].x * w0 + xin[rr].y * w1 +
                                   xin[rr].z * w2 + xin[rr].w * w3;
            }
        }
    }
    __syncthreads();  // all reads of in/wlds done before out-write (may alias)
#pragma unroll
    for (int jj = 0; jj < JJ; ++jj) {
        const int j = jg + 32 * jj;
        if (j < M) {
#pragma unroll
            for (int rr = 0; rr < RPT; ++rr) {
                const int r = rg * RPT + rr;
                float v = acc[rr][jj];
                if (RELU) v = fmaxf(v, 0.f);
                if (OB16) ((bf16*)outp)[r * sO + j] = __float2bfloat16(v);
                else      ((float*)outp)[r * sO + j] = v;
            }
        }
    }
}

// ---------------------------------------------------------------------------
// K1: pu = relu(u_t @ w1^T + b1) @ w2^T + b2, 64 rows/block, 256 threads.
// Static LDS ~46.6 KB. Output bf16 into chunk-local pu buffer.
// ---------------------------------------------------------------------------
__global__ __launch_bounds__(256) void phi_u_kernel(
    const float* __restrict__ u, const float* __restrict__ w1, const float* __restrict__ b1,
    const float* __restrict__ w2, const float* __restrict__ b2,
    bf16* __restrict__ pu, int s0)
{
    __shared__ __align__(16) float wlds[128 * 17];
    __shared__ __align__(16) float bufu[64 * 20];
    __shared__ __align__(16) float buf1[64 * 128];
    const int tid = threadIdx.x;
    const int n0 = blockIdx.x * 64;          // chunk-local row = bl*TT + t
    const int b = s0 + (n0 >> 11), t0 = n0 & (TT - 1);
    for (int idx = tid; idx < 64 * UDIM; idx += 256) {
        const int c = idx >> 6, r = idx & 63;  // lanes -> consecutive t (coalesced)
        bufu[r * 20 + c] = u[((size_t)b * UDIM + c) * TT + t0 + r];
    }
    lin_stage<256, 8, 4, 128, 16, 0, 16, true , false>(bufu, 20, nullptr, 0, w1, b1, buf1, 128, wlds);
    lin_stage<256, 8, 4, 128, 128, 0, 16, false, true >(buf1, 128, nullptr, 0, w2, b2,
                                                        pu + (size_t)n0 * HH, HH, wlds);
}

// ---------------------------------------------------------------------------
// Sequential GRU pass, one layer. One block per chunk-sample, 512 threads.
// 1536 half-row tasks of 64 MACs grouped by matrix-part: p=tid>>7
// (0:wih lo,1:wih hi,2:whh lo,3:whh hi), q=tid&127, rows 3q..3q+2 of part p
// share ONE vector slice -> 16 broadcast ds_read_b128 feed 192 FMAs/thread.
// 192 weight floats/thread in VGPRs (launch_bounds(512,2) -> 256-VGPR class).
// Trajectories bf16; recurrence state fp32. store_prev=1 emits the state
// ENTERING step t. h_out may alias x_in (same-thread read-t+1-before-write-t).
// ---------------------------------------------------------------------------
__global__ __launch_bounds__(512, 2) void gru_pass_kernel(
    const bf16* __restrict__ x_in,   // (C*T, H) chunk-local
    const float* __restrict__ wih,   // (3H, H)
    const float* __restrict__ whh,   // (3H, H)
    const float* __restrict__ h0_l,  // (B, H) global
    bf16* __restrict__ h_out,        // (C*T, H) chunk-local
    int store_prev, int s0)
{
    const int t = threadIdx.x;  // 0..511
    __shared__ __align__(16) float x_lds[HH];
    __shared__ __align__(16) float h_lds[HH];
    __shared__ __align__(16) float ps[1536];

    const int p = t >> 7;        // wave-uniform matrix part
    const int q = t & 127;
    const int co = (p & 1) * 64;
    const float* Wsrc = ((p < 2) ? wih : whh);
    const float* vec = ((p < 2) ? x_lds : h_lds) + co;

    float w[3][64];
#pragma unroll
    for (int i = 0; i < 3; ++i) {
        const float* src = Wsrc + (3 * q + i) * HH + co;
#pragma unroll
        for (int k = 0; k < 64; k += 4) {
            const float4 wv = *reinterpret_cast<const float4*>(&src[k]);
            w[i][k] = wv.x; w[i][k + 1] = wv.y; w[i][k + 2] = wv.z; w[i][k + 3] = wv.w;
        }
    }
    const int psbase = p * 384 + 3 * q;

    const bf16* xb = x_in + (size_t)blockIdx.x * TT * HH;
    bf16* ob = h_out + (size_t)blockIdx.x * TT * HH;
    float hreg = 0.f;
    if (t < HH) {
        hreg = h0_l[(s0 + blockIdx.x) * HH + t];
        h_lds[t] = hreg;
        x_lds[t] = __bfloat162float(xb[t]);
    }
    __syncthreads();

#pragma unroll 1
    for (int step = 0; step < TT; ++step) {
        float xnext = 0.f;
        if (t < HH && step + 1 < TT)
            xnext = __bfloat162float(xb[(size_t)(step + 1) * HH + t]);  // prefetch
        float a0 = 0.f, a1 = 0.f, a2 = 0.f;
#pragma unroll
        for (int k = 0; k < 64; k += 4) {
            const float4 v = *reinterpret_cast<const float4*>(&vec[k]);
            a0 += v.x * w[0][k] + v.y * w[0][k + 1] + v.z * w[0][k + 2] + v.w * w[0][k + 3];
            a1 += v.x * w[1][k] + v.y * w[1][k + 1] + v.z * w[1][k + 2] + v.w * w[1][k + 3];
            a2 += v.x * w[2][k] + v.y * w[2][k + 1] + v.z * w[2][k + 2] + v.w * w[2][k + 3];
        }
        ps[psbase] = a0; ps[psbase + 1] = a1; ps[psbase + 2] = a2;
        __syncthreads();   // ps ready; all x_lds/h_lds reads done
        if (t < HH) {
            const float gir = ps[t]       + ps[384 + t];
            const float giz = ps[t + 128] + ps[512 + t];
            const float gin = ps[t + 256] + ps[640 + t];
            const float ghr = ps[768 + t]  + ps[1152 + t];
            const float ghz = ps[896 + t]  + ps[1280 + t];
            const float ghn = ps[1024 + t] + ps[1408 + t];
            const float rg = 1.f / (1.f + __expf(-(gir + ghr)));
            const float zg = 1.f / (1.f + __expf(-(giz + ghz)));
            const float narg = gin + rg * ghn;
            const float e2 = __expf(2.f * fabsf(narg));
            float ng = 1.f - 2.f / (e2 + 1.f);          // |tanh|, inf-safe
            ng = (narg < 0.f) ? -ng : ng;
            const float hn = (1.f - zg) * ng + zg * hreg;
            ob[(size_t)step * HH + t] = __float2bfloat16(store_prev ? hreg : hn);
            h_lds[t] = hn;
            x_lds[t] = xnext;
            hreg = hn;
        }
        __syncthreads();   // h/x updated for next step
    }
}

// ---------------------------------------------------------------------------
// K6: head — dynn -> x_mean -> phi_x -> menn -> squared-error loss.
// 32 rows/block, 512 threads. Static LDS ~57.9 KB (<64 KB).
// ---------------------------------------------------------------------------
__global__ __launch_bounds__(512) void head_kernel(
    const bf16* __restrict__ pu, const bf16* __restrict__ hlast, const float* __restrict__ y_g,
    const float* __restrict__ dw1, const float* __restrict__ db1,
    const float* __restrict__ dw2, const float* __restrict__ db2,
    const float* __restrict__ xw, const float* __restrict__ xb,
    const float* __restrict__ pxw1, const float* __restrict__ pxb1,
    const float* __restrict__ pxw2, const float* __restrict__ pxb2,
    const float* __restrict__ mw1, const float* __restrict__ mb1,
    const float* __restrict__ mw2, const float* __restrict__ mb2,
    float* __restrict__ out, int s0)
{
    __shared__ __align__(16) float wlds[128 * 17];
    __shared__ __align__(16) float bufA[32 * 128];
    __shared__ __align__(16) float bufB[32 * 128];
    __shared__ __align__(16) float bufC[32 * 128];
    __shared__ float red[8];
    const int tid = threadIdx.x;
    const int n0 = blockIdx.x * 32;          // chunk-local row
    const int b = s0 + (n0 >> 11), t0 = n0 & (TT - 1);
    for (int idx = tid; idx < 32 * HH; idx += 512) {
        const int r = idx >> 7, k = idx & 127;
        bufA[r * 128 + k] = __bfloat162float(pu[(size_t)(n0 + r) * HH + k]);
        bufB[r * 128 + k] = __bfloat162float(hlast[(size_t)(n0 + r) * HH + k]);
    }
    lin_stage<512, 2, 4, 128, 128, 128, 16, true , false>(bufA, 128, bufB, 128, dw1, db1, bufC, 128, wlds); // dynn hid
    lin_stage<512, 2, 4, 128, 128,   0, 16, false, false>(bufC, 128, nullptr, 0, dw2, db2, bufA, 128, wlds); // d
    lin_stage<512, 2, 1,  32, 128,   0, 16, false, false>(bufA, 128, nullptr, 0, xw,  xb,  bufB, 128, wlds); // x_t
    lin_stage<512, 2, 4, 128,  32,   0, 16, true , false>(bufB, 128, nullptr, 0, pxw1, pxb1, bufC, 128, wlds); // phi_x hid
    lin_stage<512, 2, 4, 128, 128,   0, 16, false, false>(bufC, 128, nullptr, 0, pxw2, pxb2, bufA, 128, wlds); // px
    lin_stage<512, 2, 4, 128, 128,   0, 16, true , false>(bufA, 128, nullptr, 0, mw1, mb1, bufC, 128, wlds); // menn hid
    lin_stage<512, 2, 1,  16, 128,   0, 16, false, false>(bufC, 128, nullptr, 0, mw2, mb2, bufB, 128, wlds); // y_hat
    __syncthreads();
    // loss: one element per thread (32 rows x 16 cols = 512)
    const int r = tid >> 4, jc = tid & 15;
    const float yh = bufB[r * 128 + jc];
    const float yv = y_g[((size_t)b * YDIM + jc) * TT + t0 + r];
    float part = (yh - yv) * (yh - yv);
#pragma unroll
    for (int off = 32; off > 0; off >>= 1) part += __shfl_down(part, off, 64);
    if ((tid & 63) == 0) red[tid >> 6] = part;
    __syncthreads();
    if (tid == 0) {
        float s = 0.f;
#pragma unroll
        for (int i = 0; i < 8; ++i) s += red[i];
        atomicAdd(out, s);
    }
}

__global__ void zero_out_kernel(float* o) { o[0] = 0.f; }

extern "C" void kernel_launch(void* const* d_in, const int* in_sizes, int n_in,
                              void* d_out, int out_size, void* d_ws, size_t ws_size,
                              hipStream_t stream)
{
    (void)in_sizes; (void)n_in; (void)out_size;
    const float* u    = (const float*)d_in[0];
    const float* y    = (const float*)d_in[1];
    const float* h0   = (const float*)d_in[2];
    const float* puw1 = (const float*)d_in[3];
    const float* pub1 = (const float*)d_in[4];
    const float* puw2 = (const float*)d_in[5];
    const float* pub2 = (const float*)d_in[6];
    const float* dw1  = (const float*)d_in[7];
    const float* db1  = (const float*)d_in[8];
    const float* dw2  = (const float*)d_in[9];
    const float* db2  = (const float*)d_in[10];
    const float* xw   = (const float*)d_in[11];
    const float* xbi  = (const float*)d_in[12];
    const float* pxw1 = (const float*)d_in[13];
    const float* pxb1 = (const float*)d_in[14];
    const float* pxw2 = (const float*)d_in[15];
    const float* pxb2 = (const float*)d_in[16];
    const float* mw1  = (const float*)d_in[17];
    const float* mb1  = (const float*)d_in[18];
    const float* mw2  = (const float*)d_in[19];
    const float* mb2  = (const float*)d_in[20];
    const float* gwih = (const float*)d_in[21];
    const float* gwhh = (const float*)d_in[22];

    // Chunked over batch: per-sample scratch = pu (T*H bf16) + traj (T*H bf16) = 1 MB.
    const size_t per_sample = (size_t)TT * HH * 2 * 2;
    int C = BB;
    while (C > 1 && (size_t)C * per_sample > ws_size) C >>= 1;
    bf16* puB = (bf16*)d_ws;                        // (C*T, H)
    bf16* trB = puB + (size_t)C * TT * HH;          // (C*T, H); pass-B out aliases in

    zero_out_kernel<<<1, 1, 0, stream>>>((float*)d_out);
    for (int s0 = 0; s0 < BB; s0 += C) {
        phi_u_kernel<<<C * TT / 64, 256, 0, stream>>>(u, puw1, pub1, puw2, pub2, puB, s0);
        gru_pass_kernel<<<C, 512, 0, stream>>>(puB, gwih, gwhh, h0, trB, 0, s0);
        gru_pass_kernel<<<C, 512, 0, stream>>>(trB, gwih + H3 * HH, gwhh + H3 * HH,
                                               h0 + BB * HH, trB, 1, s0);
        head_kernel<<<C * TT / 32, 512, 0, stream>>>(puB, trB, y,
                                                     dw1, db1, dw2, db2, xw, xbi,
                                                     pxw1, pxb1, pxw2, pxb2,
                                                     mw1, mb1, mw2, mb2, (float*)d_out, s0);
    }
}

// Round 5
// 17047.652 us; speedup vs baseline: 5.1721x; 5.1721x over previous
//
#include <hip/hip_runtime.h>
#include <hip/hip_bf16.h>

#define TT 2048
#define BB 256
#define HH 128
#define UDIM 16
#define YDIM 16
#define ZDIM 32
#define H3 384

typedef __hip_bfloat16 bf16;

constexpr int clog2(int x) { return x <= 1 ? 0 : 1 + clog2(x >> 1); }

// ---------------------------------------------------------------------------
// Generic staged linear (used by phi_u only now).
// ---------------------------------------------------------------------------
template <int THREADS, int RPT, int JJ, int M, int K1, int K2, int KC, bool RELU, bool OB16>
__device__ void lin_stage(const float* __restrict__ inA, int sA,
                          const float* __restrict__ inB, int sB,
                          const float* __restrict__ Wg, const float* __restrict__ bg,
                          void* __restrict__ outp, int sO,
                          float* __restrict__ wlds)
{
    const int tid = threadIdx.x;
    const int rg = tid >> 5, jg = tid & 31;
    constexpr int K = K1 + K2;
    constexpr int LKC = clog2(KC);
    constexpr int WS = KC + 1;
    float acc[RPT][JJ];
#pragma unroll
    for (int jj = 0; jj < JJ; ++jj) {
        const int j = jg + 32 * jj;
        const float bv = (j < M) ? bg[j] : 0.f;
#pragma unroll
        for (int rr = 0; rr < RPT; ++rr) acc[rr][jj] = bv;
    }
#pragma unroll
    for (int k0 = 0; k0 < K; k0 += KC) {
        __syncthreads();
        for (int idx = tid; idx < M * KC; idx += THREADS) {
            const int j = idx >> LKC, k = idx & (KC - 1);
            wlds[j * WS + k] = Wg[j * K + k0 + k];
        }
        __syncthreads();
        const float* src = (k0 < K1) ? (inA + k0) : (inB + (k0 - K1));
        const int ss = (k0 < K1) ? sA : sB;
#pragma unroll
        for (int k = 0; k < KC; k += 4) {
            float4 xin[RPT];
#pragma unroll
            for (int rr = 0; rr < RPT; ++rr) {
                const int r = rg * RPT + rr;
                xin[rr] = *reinterpret_cast<const float4*>(&src[r * ss + k]);
            }
#pragma unroll
            for (int jj = 0; jj < JJ; ++jj) {
                const int j = jg + 32 * jj;
                const float* wr = &wlds[j * WS + k];
                const float w0 = wr[0], w1 = wr[1], w2 = wr[2], w3 = wr[3];
#pragma unroll
                for (int rr = 0; rr < RPT; ++rr)
                    acc[rr][jj] += xin[rr].x * w0 + xin[rr].y * w1 +
                                   xin[rr].z * w2 + xin[rr].w * w3;
            }
        }
    }
    __syncthreads();
#pragma unroll
    for (int jj = 0; jj < JJ; ++jj) {
        const int j = jg + 32 * jj;
        if (j < M) {
#pragma unroll
            for (int rr = 0; rr < RPT; ++rr) {
                const int r = rg * RPT + rr;
                float v = acc[rr][jj];
                if (RELU) v = fmaxf(v, 0.f);
                if (OB16) ((bf16*)outp)[r * sO + j] = __float2bfloat16(v);
                else      ((float*)outp)[r * sO + j] = v;
            }
        }
    }
}

// ---------------------------------------------------------------------------
// K1: pu = relu(u_t @ w1^T + b1) @ w2^T + b2, 64 rows/block, 256 threads.
// ---------------------------------------------------------------------------
__global__ __launch_bounds__(256) void phi_u_kernel(
    const float* __restrict__ u, const float* __restrict__ w1, const float* __restrict__ b1,
    const float* __restrict__ w2, const float* __restrict__ b2,
    bf16* __restrict__ pu, int s0)
{
    __shared__ __align__(16) float wlds[128 * 17];
    __shared__ __align__(16) float bufu[64 * 20];
    __shared__ __align__(16) float buf1[64 * 128];
    const int tid = threadIdx.x;
    const int n0 = blockIdx.x * 64;
    const int b = s0 + (n0 >> 11), t0 = n0 & (TT - 1);
    for (int idx = tid; idx < 64 * UDIM; idx += 256) {
        const int c = idx >> 6, r = idx & 63;
        bufu[r * 20 + c] = u[((size_t)b * UDIM + c) * TT + t0 + r];
    }
    lin_stage<256, 8, 4, 128, 16, 0, 16, true , false>(bufu, 20, nullptr, 0, w1, b1, buf1, 128, wlds);
    lin_stage<256, 8, 4, 128, 128, 0, 16, false, true >(buf1, 128, nullptr, 0, w2, b2,
                                                        pu + (size_t)n0 * HH, HH, wlds);
}

// ---------------------------------------------------------------------------
// Sequential GRU pass (unchanged from round 4 — correct, not yet the profiled
// bottleneck).
// ---------------------------------------------------------------------------
__global__ __launch_bounds__(512, 2) void gru_pass_kernel(
    const bf16* __restrict__ x_in, const float* __restrict__ wih,
    const float* __restrict__ whh, const float* __restrict__ h0_l,
    bf16* __restrict__ h_out, int store_prev, int s0)
{
    const int t = threadIdx.x;
    __shared__ __align__(16) float x_lds[HH];
    __shared__ __align__(16) float h_lds[HH];
    __shared__ __align__(16) float ps[1536];

    const int p = t >> 7;
    const int q = t & 127;
    const int co = (p & 1) * 64;
    const float* Wsrc = ((p < 2) ? wih : whh);
    const float* vec = ((p < 2) ? x_lds : h_lds) + co;

    float w[3][64];
#pragma unroll
    for (int i = 0; i < 3; ++i) {
        const float* src = Wsrc + (3 * q + i) * HH + co;
#pragma unroll
        for (int k = 0; k < 64; k += 4) {
            const float4 wv = *reinterpret_cast<const float4*>(&src[k]);
            w[i][k] = wv.x; w[i][k + 1] = wv.y; w[i][k + 2] = wv.z; w[i][k + 3] = wv.w;
        }
    }
    const int psbase = p * 384 + 3 * q;

    const bf16* xb = x_in + (size_t)blockIdx.x * TT * HH;
    bf16* ob = h_out + (size_t)blockIdx.x * TT * HH;
    float hreg = 0.f;
    if (t < HH) {
        hreg = h0_l[(s0 + blockIdx.x) * HH + t];
        h_lds[t] = hreg;
        x_lds[t] = __bfloat162float(xb[t]);
    }
    __syncthreads();

#pragma unroll 1
    for (int step = 0; step < TT; ++step) {
        float xnext = 0.f;
        if (t < HH && step + 1 < TT)
            xnext = __bfloat162float(xb[(size_t)(step + 1) * HH + t]);
        float a0 = 0.f, a1 = 0.f, a2 = 0.f;
#pragma unroll
        for (int k = 0; k < 64; k += 4) {
            const float4 v = *reinterpret_cast<const float4*>(&vec[k]);
            a0 += v.x * w[0][k] + v.y * w[0][k + 1] + v.z * w[0][k + 2] + v.w * w[0][k + 3];
            a1 += v.x * w[1][k] + v.y * w[1][k + 1] + v.z * w[1][k + 2] + v.w * w[1][k + 3];
            a2 += v.x * w[2][k] + v.y * w[2][k + 1] + v.z * w[2][k + 2] + v.w * w[2][k + 3];
        }
        ps[psbase] = a0; ps[psbase + 1] = a1; ps[psbase + 2] = a2;
        __syncthreads();
        if (t < HH) {
            const float gir = ps[t]       + ps[384 + t];
            const float giz = ps[t + 128] + ps[512 + t];
            const float gin = ps[t + 256] + ps[640 + t];
            const float ghr = ps[768 + t]  + ps[1152 + t];
            const float ghz = ps[896 + t]  + ps[1280 + t];
            const float ghn = ps[1024 + t] + ps[1408 + t];
            const float rg = 1.f / (1.f + __expf(-(gir + ghr)));
            const float zg = 1.f / (1.f + __expf(-(giz + ghz)));
            const float narg = gin + rg * ghn;
            const float e2 = __expf(2.f * fabsf(narg));
            float ng = 1.f - 2.f / (e2 + 1.f);
            ng = (narg < 0.f) ? -ng : ng;
            const float hn = (1.f - zg) * ng + zg * hreg;
            ob[(size_t)step * HH + t] = __float2bfloat16(store_prev ? hreg : hn);
            h_lds[t] = hn;
            x_lds[t] = xnext;
            hreg = hn;
        }
        __syncthreads();
    }
}

// ---------------------------------------------------------------------------
// head v2: ALL weights in registers (180 f32/thread over 512 threads).
// Uniform stage mapping (M,K,O with O*M=1024, F=K/O): thread T owns output
// rows jb=T&(M/2-1) and jb+M/2, col-chunk o=T>>log2(M/2) of length F.
// Per 8-row batch: partials -> ps[r*1024 + o*M + j] (lane-consecutive,
// conflict-free), barrier, 2-output/thread reduce (+bias,+ReLU) -> LDS buf,
// barrier. x reads are wave-broadcast float4s (one LDS access per wave for
// M=128 stages). No weight staging, no scalar weight reads, 14 barriers/batch.
// ---------------------------------------------------------------------------
template <int M_, int K_, int O_, bool RELU_>
__device__ __forceinline__ void rstage(const float* __restrict__ wfrag,   // [2][F]
                                       const float* __restrict__ xin, int XS,
                                       float* __restrict__ ps,
                                       const float* __restrict__ bias,
                                       float* __restrict__ outb)          // [8][M_]
{
    constexpr int F = K_ / O_;
    const int T = threadIdx.x;
    const int jb = T & (M_ / 2 - 1);
    const int o  = T >> clog2(M_ / 2);
#pragma unroll
    for (int r = 0; r < 8; ++r) {
        float a0 = 0.f, a1 = 0.f;
#pragma unroll
        for (int g = 0; g < F; g += 4) {
            const float4 xv = *reinterpret_cast<const float4*>(&xin[r * XS + o * F + g]);
            a0 += xv.x * wfrag[g]     + xv.y * wfrag[g + 1]
                + xv.z * wfrag[g + 2] + xv.w * wfrag[g + 3];
            a1 += xv.x * wfrag[F + g]     + xv.y * wfrag[F + g + 1]
                + xv.z * wfrag[F + g + 2] + xv.w * wfrag[F + g + 3];
        }
        ps[r * 1024 + o * M_ + jb]           = a0;
        ps[r * 1024 + o * M_ + jb + M_ / 2]  = a1;
    }
    __syncthreads();
    for (int oi = T; oi < 8 * M_; oi += 512) {
        const int r = oi >> clog2(M_);
        const int j = oi & (M_ - 1);
        float s = bias[j];
#pragma unroll
        for (int o2 = 0; o2 < O_; ++o2) s += ps[r * 1024 + o2 * M_ + j];
        if (RELU_) s = fmaxf(s, 0.f);
        outb[r * M_ + j] = s;
    }
    __syncthreads();
}

template <int M_, int K_, int O_>
__device__ __forceinline__ void loadw(float* __restrict__ wfrag, const float* __restrict__ Wg)
{
    constexpr int F = K_ / O_;
    const int T = threadIdx.x;
    const int jb = T & (M_ / 2 - 1);
    const int o  = T >> clog2(M_ / 2);
#pragma unroll
    for (int h = 0; h < 2; ++h)
#pragma unroll
        for (int g = 0; g < F; g += 4)
            *reinterpret_cast<float4*>(&wfrag[h * F + g]) =
                *reinterpret_cast<const float4*>(&Wg[(jb + h * (M_ / 2)) * K_ + o * F + g]);
}

__device__ __forceinline__ void stage_xc(float* __restrict__ xc,
                                         const bf16* __restrict__ pu,
                                         const bf16* __restrict__ hl,
                                         int n0, int rb)
{
    const int T = threadIdx.x;
    const int base = n0 + rb * 8;
#pragma unroll
    for (int i = 0; i < 4; ++i) {
        const int idx = T + i * 512;
        const int r = idx >> 8, k = idx & 255;
        const size_t row = (size_t)(base + r);
        xc[r * 256 + k] = (k < 128) ? __bfloat162float(pu[row * HH + k])
                                    : __bfloat162float(hl[row * HH + (k - 128)]);
    }
}

__global__ __launch_bounds__(512, 2) void head_kernel(
    const bf16* __restrict__ pu, const bf16* __restrict__ hlast, const float* __restrict__ y_g,
    const float* __restrict__ dw1, const float* __restrict__ db1,
    const float* __restrict__ dw2, const float* __restrict__ db2,
    const float* __restrict__ xw, const float* __restrict__ xb,
    const float* __restrict__ pxw1, const float* __restrict__ pxb1,
    const float* __restrict__ pxw2, const float* __restrict__ pxb2,
    const float* __restrict__ mw1, const float* __restrict__ mb1,
    const float* __restrict__ mw2, const float* __restrict__ mb2,
    float* __restrict__ out, int s0, int nrows)
{
    __shared__ __align__(16) float ps[8192];
    __shared__ __align__(16) float xc[8 * 256];
    __shared__ __align__(16) float bP[8 * 128];
    __shared__ __align__(16) float bQ[8 * 128];
    __shared__ __align__(16) float bX[8 * 32];
    __shared__ __align__(16) float bias_l[688];
    __shared__ float red[8];
    const int T = threadIdx.x;

    if (T < 128) bias_l[T]       = db1[T];
    if (T < 128) bias_l[128 + T] = db2[T];
    if (T < 32)  bias_l[256 + T] = xb[T];
    if (T < 128) bias_l[288 + T] = pxb1[T];
    if (T < 128) bias_l[416 + T] = pxb2[T];
    if (T < 128) bias_l[544 + T] = mb1[T];
    if (T < 16)  bias_l[672 + T] = mb2[T];

    float w1[64]; loadw<128, 256, 8 >(w1, dw1);
    float w2[32]; loadw<128, 128, 8 >(w2, dw2);
    float w3[8];  loadw<32,  128, 32>(w3, xw);
    float w4[8];  loadw<128, 32,  8 >(w4, pxw1);
    float w5[32]; loadw<128, 128, 8 >(w5, pxw2);
    float w6[32]; loadw<128, 128, 8 >(w6, mw1);
    const int jb7 = T & 7, o7 = T >> 3;   // S7: M=16,K=128,O=64,F=2
    float w7[4];
    w7[0] = mw2[jb7 * 128 + 2 * o7];       w7[1] = mw2[jb7 * 128 + 2 * o7 + 1];
    w7[2] = mw2[(jb7 + 8) * 128 + 2 * o7]; w7[3] = mw2[(jb7 + 8) * 128 + 2 * o7 + 1];

    float lossreg = 0.f;

    for (int tile = blockIdx.x; tile < nrows / 32; tile += gridDim.x) {
        const int n0 = tile * 32;
        const int b  = s0 + (n0 >> 11);
        const int t0 = n0 & (TT - 1);
        stage_xc(xc, pu, hlast, n0, 0);
#pragma unroll 1
        for (int rb = 0; rb < 4; ++rb) {
            __syncthreads();   // xc ready; ps free from previous batch
            rstage<128, 256, 8,  true >(w1, xc, 256, ps, bias_l + 0,   bP);
            rstage<128, 128, 8,  false>(w2, bP, 128, ps, bias_l + 128, bQ);
            rstage<32,  128, 32, false>(w3, bQ, 128, ps, bias_l + 256, bX);
            rstage<128, 32,  8,  true >(w4, bX, 32,  ps, bias_l + 288, bP);
            rstage<128, 128, 8,  false>(w5, bP, 128, ps, bias_l + 416, bQ);
            rstage<128, 128, 8,  true >(w6, bQ, 128, ps, bias_l + 544, bP);
            // S7 partials + prefetch next batch's xc
#pragma unroll
            for (int r = 0; r < 8; ++r) {
                const float x0 = bP[r * 128 + 2 * o7], x1 = bP[r * 128 + 2 * o7 + 1];
                ps[r * 1024 + o7 * 16 + jb7]     = x0 * w7[0] + x1 * w7[1];
                ps[r * 1024 + o7 * 16 + jb7 + 8] = x0 * w7[2] + x1 * w7[3];
            }
            if (rb < 3) stage_xc(xc, pu, hlast, n0, rb + 1);
            __syncthreads();
            if (T < 128) {
                const int r = T >> 4, j = T & 15;
                float s = bias_l[672 + j];
#pragma unroll
                for (int o2 = 0; o2 < 64; ++o2) s += ps[r * 1024 + o2 * 16 + j];
                const int trow = t0 + rb * 8 + r;
                const float yv = y_g[((size_t)b * YDIM + j) * TT + trow];
                const float d = s - yv;
                lossreg += d * d;
            }
            // loop-top barrier closes this batch
        }
    }
    __syncthreads();
#pragma unroll
    for (int off = 32; off > 0; off >>= 1) lossreg += __shfl_down(lossreg, off, 64);
    if ((T & 63) == 0) red[T >> 6] = lossreg;
    __syncthreads();
    if (T == 0) {
        float s = 0.f;
#pragma unroll
        for (int i = 0; i < 8; ++i) s += red[i];
        atomicAdd(out, s);
    }
}

__global__ void zero_out_kernel(float* o) { o[0] = 0.f; }

extern "C" void kernel_launch(void* const* d_in, const int* in_sizes, int n_in,
                              void* d_out, int out_size, void* d_ws, size_t ws_size,
                              hipStream_t stream)
{
    (void)in_sizes; (void)n_in; (void)out_size;
    const float* u    = (const float*)d_in[0];
    const float* y    = (const float*)d_in[1];
    const float* h0   = (const float*)d_in[2];
    const float* puw1 = (const float*)d_in[3];
    const float* pub1 = (const float*)d_in[4];
    const float* puw2 = (const float*)d_in[5];
    const float* pub2 = (const float*)d_in[6];
    const float* dw1  = (const float*)d_in[7];
    const float* db1  = (const float*)d_in[8];
    const float* dw2  = (const float*)d_in[9];
    const float* db2  = (const float*)d_in[10];
    const float* xw   = (const float*)d_in[11];
    const float* xbi  = (const float*)d_in[12];
    const float* pxw1 = (const float*)d_in[13];
    const float* pxb1 = (const float*)d_in[14];
    const float* pxw2 = (const float*)d_in[15];
    const float* pxb2 = (const float*)d_in[16];
    const float* mw1  = (const float*)d_in[17];
    const float* mb1  = (const float*)d_in[18];
    const float* mw2  = (const float*)d_in[19];
    const float* mb2  = (const float*)d_in[20];
    const float* gwih = (const float*)d_in[21];
    const float* gwhh = (const float*)d_in[22];

    const size_t per_sample = (size_t)TT * HH * 2 * 2;
    int C = BB;
    while (C > 1 && (size_t)C * per_sample > ws_size) C >>= 1;
    bf16* puB = (bf16*)d_ws;
    bf16* trB = puB + (size_t)C * TT * HH;

    zero_out_kernel<<<1, 1, 0, stream>>>((float*)d_out);
    for (int s0 = 0; s0 < BB; s0 += C) {
        phi_u_kernel<<<C * TT / 64, 256, 0, stream>>>(u, puw1, pub1, puw2, pub2, puB, s0);
        gru_pass_kernel<<<C, 512, 0, stream>>>(puB, gwih, gwhh, h0, trB, 0, s0);
        gru_pass_kernel<<<C, 512, 0, stream>>>(trB, gwih + H3 * HH, gwhh + H3 * HH,
                                               h0 + BB * HH, trB, 1, s0);
        head_kernel<<<512, 512, 0, stream>>>(puB, trB, y,
                                             dw1, db1, dw2, db2, xw, xbi,
                                             pxw1, pxb1, pxw2, pxb2,
                                             mw1, mb1, mw2, mb2,
                                             (float*)d_out, s0, C * TT);
    }
}

// Round 6
// 7394.575 us; speedup vs baseline: 11.9238x; 2.3054x over previous
//
#include <hip/hip_runtime.h>
#include <hip/hip_bf16.h>

#define TT 2048
#define BB 256
#define HH 128
#define UDIM 16
#define YDIM 16
#define ZDIM 32
#define H3 384

typedef __hip_bfloat16 bf16;

constexpr int clog2(int x) { return x <= 1 ? 0 : 1 + clog2(x >> 1); }

// ---------------------------------------------------------------------------
// Register-weight linear stage. Mapping (M,K,O with O*(M/2)=512, F=K/O):
// thread T owns output rows jb=T&(M/2-1) and jb+M/2, col-chunk o=T>>log2(M/2)
// of length F. Partials -> ps[r*1024 + o*M + j] (lane-consecutive,
// conflict-free), barrier, 2-output/thread reduce (+bias,+ReLU) -> outb,
// barrier. outb may alias xin (xin reads all complete before the barrier).
// ---------------------------------------------------------------------------
template <int M_, int K_, int O_, bool RELU_>
__device__ __forceinline__ void rstage(const float* __restrict__ wfrag,   // [2][F]
                                       const float* __restrict__ xin, int XS,
                                       float* __restrict__ ps,
                                       const float* __restrict__ bias,
                                       float* __restrict__ outb)          // [8][M_]
{
    constexpr int F = K_ / O_;
    const int T = threadIdx.x;
    const int jb = T & (M_ / 2 - 1);
    const int o  = T >> clog2(M_ / 2);
#pragma unroll
    for (int r = 0; r < 8; ++r) {
        float a0 = 0.f, a1 = 0.f;
#pragma unroll
        for (int g = 0; g < F; g += 4) {
            const float4 xv = *reinterpret_cast<const float4*>(&xin[r * XS + o * F + g]);
            a0 += xv.x * wfrag[g]     + xv.y * wfrag[g + 1]
                + xv.z * wfrag[g + 2] + xv.w * wfrag[g + 3];
            a1 += xv.x * wfrag[F + g]     + xv.y * wfrag[F + g + 1]
                + xv.z * wfrag[F + g + 2] + xv.w * wfrag[F + g + 3];
        }
        ps[r * 1024 + o * M_ + jb]           = a0;
        ps[r * 1024 + o * M_ + jb + M_ / 2]  = a1;
    }
    __syncthreads();
    for (int oi = T; oi < 8 * M_; oi += 512) {
        const int r = oi >> clog2(M_);
        const int j = oi & (M_ - 1);
        float s = bias[j];
#pragma unroll
        for (int o2 = 0; o2 < O_; ++o2) s += ps[r * 1024 + o2 * M_ + j];
        if (RELU_) s = fmaxf(s, 0.f);
        outb[r * M_ + j] = s;
    }
    __syncthreads();
}

template <int M_, int K_, int O_>
__device__ __forceinline__ void loadw(float* __restrict__ wfrag, const float* __restrict__ Wg)
{
    constexpr int F = K_ / O_;
    const int T = threadIdx.x;
    const int jb = T & (M_ / 2 - 1);
    const int o  = T >> clog2(M_ / 2);
#pragma unroll
    for (int h = 0; h < 2; ++h)
#pragma unroll
        for (int g = 0; g < F; g += 4)
            *reinterpret_cast<float4*>(&wfrag[h * F + g]) =
                *reinterpret_cast<const float4*>(&Wg[(jb + h * (M_ / 2)) * K_ + o * F + g]);
}

// ---------------------------------------------------------------------------
// phi_u v2: register weights (36 f32/thread), persistent 512 blocks.
// 32-row tiles, 8-row batches: stage u -> S1 (K=16, scalar-pair) -> S2
// (rstage, in-place) -> bf16 write. ~38 KB LDS, no spills.
// ---------------------------------------------------------------------------
__global__ __launch_bounds__(512, 2) void phi_u_kernel(
    const float* __restrict__ u, const float* __restrict__ w1, const float* __restrict__ b1,
    const float* __restrict__ w2, const float* __restrict__ b2,
    bf16* __restrict__ pu, int s0, int nrows)
{
    __shared__ __align__(16) float ps[8192];
    __shared__ __align__(16) float xc[8 * 16];
    __shared__ __align__(16) float bP[8 * 128];
    __shared__ __align__(16) float bias_l[256];
    const int T = threadIdx.x;
    if (T < 128) { bias_l[T] = b1[T]; bias_l[128 + T] = b2[T]; }
    const int jb = T & 63, o = T >> 6;
    float wa[4];
    wa[0] = w1[jb * 16 + o * 2];        wa[1] = w1[jb * 16 + o * 2 + 1];
    wa[2] = w1[(jb + 64) * 16 + o * 2]; wa[3] = w1[(jb + 64) * 16 + o * 2 + 1];
    float wb[32]; loadw<128, 128, 8>(wb, w2);
    __syncthreads();

    for (int tile = blockIdx.x; tile < nrows / 32; tile += gridDim.x) {
        const int n0 = tile * 32;
        const int b  = s0 + (n0 >> 11);
        const int t0 = n0 & (TT - 1);
#pragma unroll 1
        for (int rb = 0; rb < 4; ++rb) {
            if (T < 128) {
                const int r = T & 7, c = T >> 3;   // lanes -> consecutive t
                xc[r * 16 + c] = u[((size_t)b * UDIM + c) * TT + t0 + rb * 8 + r];
            }
            __syncthreads();   // xc ready; ps free
            // S1: M=128, K=16, O=8, F=2
#pragma unroll
            for (int r = 0; r < 8; ++r) {
                const float x0 = xc[r * 16 + o * 2], x1 = xc[r * 16 + o * 2 + 1];
                ps[r * 1024 + o * 128 + jb]      = x0 * wa[0] + x1 * wa[1];
                ps[r * 1024 + o * 128 + jb + 64] = x0 * wa[2] + x1 * wa[3];
            }
            __syncthreads();
            for (int oi = T; oi < 8 * 128; oi += 512) {
                const int r = oi >> 7, j = oi & 127;
                float s = bias_l[j];
#pragma unroll
                for (int o2 = 0; o2 < 8; ++o2) s += ps[r * 1024 + o2 * 128 + j];
                bP[r * 128 + j] = fmaxf(s, 0.f);
            }
            __syncthreads();
            rstage<128, 128, 8, false>(wb, bP, 128, ps, bias_l + 128, bP);  // in-place
            const int row0 = n0 + rb * 8;
            for (int oi = T; oi < 8 * 128; oi += 512) {
                const int r = oi >> 7, j = oi & 127;
                pu[(size_t)(row0 + r) * HH + j] = __float2bfloat16(bP[r * 128 + j]);
            }
            __syncthreads();   // bP reads done before next batch overwrites
        }
    }
}

// ---------------------------------------------------------------------------
// Sequential GRU pass (unchanged — next optimization target after profile).
// ---------------------------------------------------------------------------
__global__ __launch_bounds__(512, 2) void gru_pass_kernel(
    const bf16* __restrict__ x_in, const float* __restrict__ wih,
    const float* __restrict__ whh, const float* __restrict__ h0_l,
    bf16* __restrict__ h_out, int store_prev, int s0)
{
    const int t = threadIdx.x;
    __shared__ __align__(16) float x_lds[HH];
    __shared__ __align__(16) float h_lds[HH];
    __shared__ __align__(16) float ps[1536];

    const int p = t >> 7;
    const int q = t & 127;
    const int co = (p & 1) * 64;
    const float* Wsrc = ((p < 2) ? wih : whh);
    const float* vec = ((p < 2) ? x_lds : h_lds) + co;

    float w[3][64];
#pragma unroll
    for (int i = 0; i < 3; ++i) {
        const float* src = Wsrc + (3 * q + i) * HH + co;
#pragma unroll
        for (int k = 0; k < 64; k += 4) {
            const float4 wv = *reinterpret_cast<const float4*>(&src[k]);
            w[i][k] = wv.x; w[i][k + 1] = wv.y; w[i][k + 2] = wv.z; w[i][k + 3] = wv.w;
        }
    }
    const int psbase = p * 384 + 3 * q;

    const bf16* xb = x_in + (size_t)blockIdx.x * TT * HH;
    bf16* ob = h_out + (size_t)blockIdx.x * TT * HH;
    float hreg = 0.f;
    if (t < HH) {
        hreg = h0_l[(s0 + blockIdx.x) * HH + t];
        h_lds[t] = hreg;
        x_lds[t] = __bfloat162float(xb[t]);
    }
    __syncthreads();

#pragma unroll 1
    for (int step = 0; step < TT; ++step) {
        float xnext = 0.f;
        if (t < HH && step + 1 < TT)
            xnext = __bfloat162float(xb[(size_t)(step + 1) * HH + t]);
        float a0 = 0.f, a1 = 0.f, a2 = 0.f;
#pragma unroll
        for (int k = 0; k < 64; k += 4) {
            const float4 v = *reinterpret_cast<const float4*>(&vec[k]);
            a0 += v.x * w[0][k] + v.y * w[0][k + 1] + v.z * w[0][k + 2] + v.w * w[0][k + 3];
            a1 += v.x * w[1][k] + v.y * w[1][k + 1] + v.z * w[1][k + 2] + v.w * w[1][k + 3];
            a2 += v.x * w[2][k] + v.y * w[2][k + 1] + v.z * w[2][k + 2] + v.w * w[2][k + 3];
        }
        ps[psbase] = a0; ps[psbase + 1] = a1; ps[psbase + 2] = a2;
        __syncthreads();
        if (t < HH) {
            const float gir = ps[t]       + ps[384 + t];
            const float giz = ps[t + 128] + ps[512 + t];
            const float gin = ps[t + 256] + ps[640 + t];
            const float ghr = ps[768 + t]  + ps[1152 + t];
            const float ghz = ps[896 + t]  + ps[1280 + t];
            const float ghn = ps[1024 + t] + ps[1408 + t];
            const float rg = 1.f / (1.f + __expf(-(gir + ghr)));
            const float zg = 1.f / (1.f + __expf(-(giz + ghz)));
            const float narg = gin + rg * ghn;
            const float e2 = __expf(2.f * fabsf(narg));
            float ng = 1.f - 2.f / (e2 + 1.f);
            ng = (narg < 0.f) ? -ng : ng;
            const float hn = (1.f - zg) * ng + zg * hreg;
            ob[(size_t)step * HH + t] = __float2bfloat16(store_prev ? hreg : hn);
            h_lds[t] = hn;
            x_lds[t] = xnext;
            hreg = hn;
        }
        __syncthreads();
    }
}

// ---------------------------------------------------------------------------
// head v2 (unchanged from round 5): all weights in registers.
// ---------------------------------------------------------------------------
__device__ __forceinline__ void stage_xc(float* __restrict__ xc,
                                         const bf16* __restrict__ pu,
                                         const bf16* __restrict__ hl,
                                         int n0, int rb)
{
    const int T = threadIdx.x;
    const int base = n0 + rb * 8;
#pragma unroll
    for (int i = 0; i < 4; ++i) {
        const int idx = T + i * 512;
        const int r = idx >> 8, k = idx & 255;
        const size_t row = (size_t)(base + r);
        xc[r * 256 + k] = (k < 128) ? __bfloat162float(pu[row * HH + k])
                                    : __bfloat162float(hl[row * HH + (k - 128)]);
    }
}

__global__ __launch_bounds__(512, 2) void head_kernel(
    const bf16* __restrict__ pu, const bf16* __restrict__ hlast, const float* __restrict__ y_g,
    const float* __restrict__ dw1, const float* __restrict__ db1,
    const float* __restrict__ dw2, const float* __restrict__ db2,
    const float* __restrict__ xw, const float* __restrict__ xb,
    const float* __restrict__ pxw1, const float* __restrict__ pxb1,
    const float* __restrict__ pxw2, const float* __restrict__ pxb2,
    const float* __restrict__ mw1, const float* __restrict__ mb1,
    const float* __restrict__ mw2, const float* __restrict__ mb2,
    float* __restrict__ out, int s0, int nrows)
{
    __shared__ __align__(16) float ps[8192];
    __shared__ __align__(16) float xc[8 * 256];
    __shared__ __align__(16) float bP[8 * 128];
    __shared__ __align__(16) float bQ[8 * 128];
    __shared__ __align__(16) float bX[8 * 32];
    __shared__ __align__(16) float bias_l[688];
    __shared__ float red[8];
    const int T = threadIdx.x;

    if (T < 128) bias_l[T]       = db1[T];
    if (T < 128) bias_l[128 + T] = db2[T];
    if (T < 32)  bias_l[256 + T] = xb[T];
    if (T < 128) bias_l[288 + T] = pxb1[T];
    if (T < 128) bias_l[416 + T] = pxb2[T];
    if (T < 128) bias_l[544 + T] = mb1[T];
    if (T < 16)  bias_l[672 + T] = mb2[T];

    float w1[64]; loadw<128, 256, 8 >(w1, dw1);
    float w2[32]; loadw<128, 128, 8 >(w2, dw2);
    float w3[8];  loadw<32,  128, 32>(w3, xw);
    float w4[8];  loadw<128, 32,  8 >(w4, pxw1);
    float w5[32]; loadw<128, 128, 8 >(w5, pxw2);
    float w6[32]; loadw<128, 128, 8 >(w6, mw1);
    const int jb7 = T & 7, o7 = T >> 3;   // S7: M=16,K=128,O=64,F=2
    float w7[4];
    w7[0] = mw2[jb7 * 128 + 2 * o7];       w7[1] = mw2[jb7 * 128 + 2 * o7 + 1];
    w7[2] = mw2[(jb7 + 8) * 128 + 2 * o7]; w7[3] = mw2[(jb7 + 8) * 128 + 2 * o7 + 1];

    float lossreg = 0.f;

    for (int tile = blockIdx.x; tile < nrows / 32; tile += gridDim.x) {
        const int n0 = tile * 32;
        const int b  = s0 + (n0 >> 11);
        const int t0 = n0 & (TT - 1);
        stage_xc(xc, pu, hlast, n0, 0);
#pragma unroll 1
        for (int rb = 0; rb < 4; ++rb) {
            __syncthreads();   // xc ready; ps free from previous batch
            rstage<128, 256, 8,  true >(w1, xc, 256, ps, bias_l + 0,   bP);
            rstage<128, 128, 8,  false>(w2, bP, 128, ps, bias_l + 128, bQ);
            rstage<32,  128, 32, false>(w3, bQ, 128, ps, bias_l + 256, bX);
            rstage<128, 32,  8,  true >(w4, bX, 32,  ps, bias_l + 288, bP);
            rstage<128, 128, 8,  false>(w5, bP, 128, ps, bias_l + 416, bQ);
            rstage<128, 128, 8,  true >(w6, bQ, 128, ps, bias_l + 544, bP);
#pragma unroll
            for (int r = 0; r < 8; ++r) {
                const float x0 = bP[r * 128 + 2 * o7], x1 = bP[r * 128 + 2 * o7 + 1];
                ps[r * 1024 + o7 * 16 + jb7]     = x0 * w7[0] + x1 * w7[1];
                ps[r * 1024 + o7 * 16 + jb7 + 8] = x0 * w7[2] + x1 * w7[3];
            }
            if (rb < 3) stage_xc(xc, pu, hlast, n0, rb + 1);
            __syncthreads();
            if (T < 128) {
                const int r = T >> 4, j = T & 15;
                float s = bias_l[672 + j];
#pragma unroll
                for (int o2 = 0; o2 < 64; ++o2) s += ps[r * 1024 + o2 * 16 + j];
                const int trow = t0 + rb * 8 + r;
                const float yv = y_g[((size_t)b * YDIM + j) * TT + trow];
                const float d = s - yv;
                lossreg += d * d;
            }
        }
    }
    __syncthreads();
#pragma unroll
    for (int off = 32; off > 0; off >>= 1) lossreg += __shfl_down(lossreg, off, 64);
    if ((T & 63) == 0) red[T >> 6] = lossreg;
    __syncthreads();
    if (T == 0) {
        float s = 0.f;
#pragma unroll
        for (int i = 0; i < 8; ++i) s += red[i];
        atomicAdd(out, s);
    }
}

__global__ void zero_out_kernel(float* o) { o[0] = 0.f; }

extern "C" void kernel_launch(void* const* d_in, const int* in_sizes, int n_in,
                              void* d_out, int out_size, void* d_ws, size_t ws_size,
                              hipStream_t stream)
{
    (void)in_sizes; (void)n_in; (void)out_size;
    const float* u    = (const float*)d_in[0];
    const float* y    = (const float*)d_in[1];
    const float* h0   = (const float*)d_in[2];
    const float* puw1 = (const float*)d_in[3];
    const float* pub1 = (const float*)d_in[4];
    const float* puw2 = (const float*)d_in[5];
    const float* pub2 = (const float*)d_in[6];
    const float* dw1  = (const float*)d_in[7];
    const float* db1  = (const float*)d_in[8];
    const float* dw2  = (const float*)d_in[9];
    const float* db2  = (const float*)d_in[10];
    const float* xw   = (const float*)d_in[11];
    const float* xbi  = (const float*)d_in[12];
    const float* pxw1 = (const float*)d_in[13];
    const float* pxb1 = (const float*)d_in[14];
    const float* pxw2 = (const float*)d_in[15];
    const float* pxb2 = (const float*)d_in[16];
    const float* mw1  = (const float*)d_in[17];
    const float* mb1  = (const float*)d_in[18];
    const float* mw2  = (const float*)d_in[19];
    const float* mb2  = (const float*)d_in[20];
    const float* gwih = (const float*)d_in[21];
    const float* gwhh = (const float*)d_in[22];

    const size_t per_sample = (size_t)TT * HH * 2 * 2;
    int C = BB;
    while (C > 1 && (size_t)C * per_sample > ws_size) C >>= 1;
    bf16* puB = (bf16*)d_ws;
    bf16* trB = puB + (size_t)C * TT * HH;

    zero_out_kernel<<<1, 1, 0, stream>>>((float*)d_out);
    for (int s0 = 0; s0 < BB; s0 += C) {
        phi_u_kernel<<<512, 512, 0, stream>>>(u, puw1, pub1, puw2, pub2, puB, s0, C * TT);
        gru_pass_kernel<<<C, 512, 0, stream>>>(puB, gwih, gwhh, h0, trB, 0, s0);
        gru_pass_kernel<<<C, 512, 0, stream>>>(trB, gwih + H3 * HH, gwhh + H3 * HH,
                                               h0 + BB * HH, trB, 1, s0);
        head_kernel<<<512, 512, 0, stream>>>(puB, trB, y,
                                             dw1, db1, dw2, db2, xw, xbi,
                                             pxw1, pxb1, pxw2, pxb2,
                                             mw1, mb1, mw2, mb2,
                                             (float*)d_out, s0, C * TT);
    }
}